// Round 2
// baseline (593.886 us; speedup 1.0000x reference)
//
#include <hip/hip_runtime.h>

// SparseConvTransposeBlock, round 2: kill the atomic scatter.
//
// R1 evidence: k1 WRITE_SIZE=540MB == every atomic fadd written through to
// HBM (2.16M rows x 256B), at 1.79 TB/s random-RMW rate -> 447us. Fix: CSR
// two-phase. Phase A computes product rows (bf16 MFMA as before) and stores
// them as bf16 at a CSR-assigned contiguous slot (plain coalesced 128B
// stores). Phase B sums each output row's contiguous slots sequentially,
// writes out once, and accumulates BN stats on the fly.
//
// Bias cancels in training-mode BN (y = (acc - mean_acc)*rsqrt(var)*g + b).

#define C_DIM 64
#define LDS_STRIDE 72  // bf16 elems per Wt row: 64 + 8 pad

typedef __bf16 bf16_t;
typedef bf16_t bf16x8 __attribute__((ext_vector_type(8)));
typedef bf16_t bf16x4 __attribute__((ext_vector_type(4)));
typedef float floatx4 __attribute__((ext_vector_type(4)));

// ---------------------------------------------------------------- CSR build
__global__ __launch_bounds__(256)
void k_hist(const int* __restrict__ pout, int* __restrict__ counts, int M)
{
    int j = blockIdx.x * 256 + threadIdx.x;
    if (j < M) atomicAdd(&counts[pout[j]], 1);
}

// per-1024-elem block sums
__global__ __launch_bounds__(256)
void k_scan_a(const int* __restrict__ counts, int* __restrict__ partials, int n)
{
    __shared__ int ls[256];
    int tid = threadIdx.x;
    int base = blockIdx.x * 1024 + tid * 4;
    int s = 0;
    #pragma unroll
    for (int j = 0; j < 4; ++j)
        if (base + j < n) s += counts[base + j];
    ls[tid] = s;
    __syncthreads();
    for (int off = 128; off > 0; off >>= 1) {
        if (tid < off) ls[tid] += ls[tid + off];
        __syncthreads();
    }
    if (tid == 0) partials[blockIdx.x] = ls[0];
}

// exclusive scan of the (<=1024) partials, single block
__global__ __launch_bounds__(1024)
void k_scan_b(int* __restrict__ partials, int nb)
{
    __shared__ int ls[1024];
    int tid = threadIdx.x;
    ls[tid] = (tid < nb) ? partials[tid] : 0;
    __syncthreads();
    if (tid == 0) {
        int run = 0;
        for (int i = 0; i < nb; ++i) { int t = ls[i]; ls[i] = run; run += t; }
    }
    __syncthreads();
    if (tid < nb) partials[tid] = ls[tid];
}

// per-block exclusive scan + add scanned partial; writes offsets AND resets
// cursor to the same values (cursor is then bumped atomically in Phase A).
__global__ __launch_bounds__(256)
void k_scan_c(int* __restrict__ cursor /* counts in, running cursor out */,
              int* __restrict__ offsets, const int* __restrict__ partials,
              int n, int M)
{
    __shared__ int ls[256];
    int tid = threadIdx.x;
    int base = blockIdx.x * 1024 + tid * 4;
    int v[4];
    #pragma unroll
    for (int j = 0; j < 4; ++j)
        v[j] = (base + j < n) ? cursor[base + j] : 0;
    int tsum = v[0] + v[1] + v[2] + v[3];
    ls[tid] = tsum;
    __syncthreads();
    for (int off = 1; off < 256; off <<= 1) {
        int t = (tid >= off) ? ls[tid - off] : 0;
        __syncthreads();
        ls[tid] += t;
        __syncthreads();
    }
    int run = partials[blockIdx.x] + ls[tid] - tsum;
    #pragma unroll
    for (int j = 0; j < 4; ++j) {
        if (base + j < n) {
            offsets[base + j] = run;
            cursor[base + j]  = run;
            run += v[j];
        }
    }
    if (blockIdx.x == 0 && tid == 0) offsets[n] = M;
}

// ------------------------------------------------- Phase A: gemm -> CSR slot
__global__ __launch_bounds__(256)
void k_gemm_store(const float* __restrict__ features,
                  const float* __restrict__ weight,
                  const int* __restrict__ pairs_in,
                  const int* __restrict__ pairs_out,
                  int* __restrict__ cursor,
                  char* __restrict__ temp,
                  int P, int rows_per_block)
{
    __shared__ bf16_t Wt[C_DIM * LDS_STRIDE];

    const int k   = blockIdx.y;
    const int tid = threadIdx.x;

    const float* Wk = weight + (size_t)k * C_DIM * C_DIM;
    for (int i = tid; i < C_DIM * C_DIM; i += 256) {
        int c = i >> 6, d = i & 63;
        Wt[d * LDS_STRIDE + c] = (bf16_t)Wk[i];
    }
    __syncthreads();

    const int wave = tid >> 6;
    const int lane = tid & 63;
    const int quad = lane >> 4;
    const int col  = lane & 15;

    // B fragments: lane holds B[kk = quad*8+j+32*ks][n = col+16*nt] = Wt[n][kk].
    bf16x8 bfrag[2][4];
    #pragma unroll
    for (int ks = 0; ks < 2; ++ks)
        #pragma unroll
        for (int nt = 0; nt < 4; ++nt)
            bfrag[ks][nt] =
                *(const bf16x8*)&Wt[(col + 16 * nt) * LDS_STRIDE + quad * 8 + 32 * ks];

    const int* __restrict__ pin  = pairs_in  + (size_t)k * P;
    const int* __restrict__ pout = pairs_out + (size_t)k * P;

    const int p0   = blockIdx.x * rows_per_block;
    const int pend = min(p0 + rows_per_block, P);

    for (int base = p0 + wave * 16; base < pend; base += 64) {
        int prow    = base + col;
        int clamped = (prow < pend) ? prow : (pend - 1);
        int in_idx  = pin[clamped];

        // Claim CSR slot: lanes 0..15 (quad 0) own rows base..base+15.
        int pos = 0;
        if (lane < 16 && prow < pend)
            pos = atomicAdd(&cursor[pout[clamped]], 1);

        const float* src = features + (size_t)in_idx * C_DIM + quad * 8;
        float4 f0 = *(const float4*)(src);
        float4 f1 = *(const float4*)(src + 4);
        float4 f2 = *(const float4*)(src + 32);
        float4 f3 = *(const float4*)(src + 36);

        bf16x8 a0, a1;
        a0[0] = (bf16_t)f0.x; a0[1] = (bf16_t)f0.y; a0[2] = (bf16_t)f0.z; a0[3] = (bf16_t)f0.w;
        a0[4] = (bf16_t)f1.x; a0[5] = (bf16_t)f1.y; a0[6] = (bf16_t)f1.z; a0[7] = (bf16_t)f1.w;
        a1[0] = (bf16_t)f2.x; a1[1] = (bf16_t)f2.y; a1[2] = (bf16_t)f2.z; a1[3] = (bf16_t)f2.w;
        a1[4] = (bf16_t)f3.x; a1[5] = (bf16_t)f3.y; a1[6] = (bf16_t)f3.z; a1[7] = (bf16_t)f3.w;

        floatx4 acc0 = {0.f, 0.f, 0.f, 0.f};
        floatx4 acc1 = {0.f, 0.f, 0.f, 0.f};
        floatx4 acc2 = {0.f, 0.f, 0.f, 0.f};
        floatx4 acc3 = {0.f, 0.f, 0.f, 0.f};

        acc0 = __builtin_amdgcn_mfma_f32_16x16x32_bf16(a0, bfrag[0][0], acc0, 0, 0, 0);
        acc0 = __builtin_amdgcn_mfma_f32_16x16x32_bf16(a1, bfrag[1][0], acc0, 0, 0, 0);
        acc1 = __builtin_amdgcn_mfma_f32_16x16x32_bf16(a0, bfrag[0][1], acc1, 0, 0, 0);
        acc1 = __builtin_amdgcn_mfma_f32_16x16x32_bf16(a1, bfrag[1][1], acc1, 0, 0, 0);
        acc2 = __builtin_amdgcn_mfma_f32_16x16x32_bf16(a0, bfrag[0][2], acc2, 0, 0, 0);
        acc2 = __builtin_amdgcn_mfma_f32_16x16x32_bf16(a1, bfrag[1][2], acc2, 0, 0, 0);
        acc3 = __builtin_amdgcn_mfma_f32_16x16x32_bf16(a0, bfrag[0][3], acc3, 0, 0, 0);
        acc3 = __builtin_amdgcn_mfma_f32_16x16x32_bf16(a1, bfrag[1][3], acc3, 0, 0, 0);

        // Store product row (bf16) at its CSR slot. Row layout: 128B, chunk
        // col holds channels {col, col+16, col+32, col+48}. 16 lanes of the
        // owning quad write 128B contiguous.
        #pragma unroll
        for (int r = 0; r < 4; ++r) {
            int m = quad * 4 + r;
            int g = __shfl(pos, m);   // lane m (<16) claimed row base+m's slot
            if (base + m < pend) {
                bf16x4 pk;
                pk[0] = (bf16_t)acc0[r];
                pk[1] = (bf16_t)acc1[r];
                pk[2] = (bf16_t)acc2[r];
                pk[3] = (bf16_t)acc3[r];
                *(bf16x4*)(temp + (size_t)g * 128 + col * 8) = pk;
            }
        }
    }
}

// ------------------------------ Phase B: segmented sum + BN stats + write out
__global__ __launch_bounds__(256)
void k_gather_sum(const char* __restrict__ temp,
                  const int* __restrict__ offsets,
                  float* __restrict__ out,
                  float* __restrict__ sums,
                  int n_rows)
{
    const int tid  = threadIdx.x;
    const int wave = tid >> 6;
    const int lane = tid & 63;
    const int quad = lane >> 4;
    const int col  = lane & 15;

    float s[4]  = {0.f, 0.f, 0.f, 0.f};
    float s2[4] = {0.f, 0.f, 0.f, 0.f};

    for (int r0 = blockIdx.x * 16; r0 < n_rows; r0 += gridDim.x * 16) {
        int r = r0 + wave * 4 + quad;
        if (r < n_rows) {
            int sbeg = offsets[r];
            int send = offsets[r + 1];
            int cnt  = send - sbeg;
            const char* p = temp + (size_t)sbeg * 128 + col * 8;

            float acc[4] = {0.f, 0.f, 0.f, 0.f};
            int i = 0;
            for (; i + 1 < cnt; i += 2) {
                bf16x4 va = *(const bf16x4*)(p);
                bf16x4 vb = *(const bf16x4*)(p + 128);
                p += 256;
                #pragma unroll
                for (int j = 0; j < 4; ++j) acc[j] += (float)va[j];
                #pragma unroll
                for (int j = 0; j < 4; ++j) acc[j] += (float)vb[j];
            }
            if (i < cnt) {
                bf16x4 va = *(const bf16x4*)(p);
                #pragma unroll
                for (int j = 0; j < 4; ++j) acc[j] += (float)va[j];
            }

            #pragma unroll
            for (int j = 0; j < 4; ++j) {
                out[(size_t)r * C_DIM + col + 16 * j] = acc[j];
                s[j]  += acc[j];
                s2[j] += acc[j] * acc[j];
            }
        }
    }

    __shared__ float ls[128];
    if (tid < 128) ls[tid] = 0.f;
    __syncthreads();
    #pragma unroll
    for (int j = 0; j < 4; ++j) {
        atomicAdd(&ls[col + 16 * j], s[j]);
        atomicAdd(&ls[64 + col + 16 * j], s2[j]);
    }
    __syncthreads();
    if (tid < 128) atomicAdd(&sums[tid], ls[tid]);
}

// --------------------------------------------------- BN normalize + ReLU
__global__ __launch_bounds__(256)
void k3_bn_relu(float* __restrict__ out, const float* __restrict__ sums,
                const float* __restrict__ gamma, const float* __restrict__ beta,
                int n_rows)
{
    int tid = blockIdx.x * 256 + threadIdx.x;
    int ch0 = (tid * 4) & 63;
    float inv_n = 1.0f / (float)n_rows;

    float sc[4], sh[4];
    #pragma unroll
    for (int j = 0; j < 4; ++j) {
        int ch    = ch0 + j;
        float m   = sums[ch] * inv_n;
        float var = sums[64 + ch] * inv_n - m * m;
        float inv = rsqrtf(var + 1e-5f);
        float g   = gamma[ch] * inv;
        sc[j] = g;
        sh[j] = beta[ch] - m * g;
    }

    size_t total = (size_t)n_rows * C_DIM / 4;
    for (size_t i = tid; i < total; i += (size_t)gridDim.x * 256) {
        float4 v = ((const float4*)out)[i];
        v.x = fmaxf(v.x * sc[0] + sh[0], 0.f);
        v.y = fmaxf(v.y * sc[1] + sh[1], 0.f);
        v.z = fmaxf(v.z * sc[2] + sh[2], 0.f);
        v.w = fmaxf(v.w * sc[3] + sh[3], 0.f);
        ((float4*)out)[i] = v;
    }
}

// ===================== fallback (R1 atomic path, known-good) ================
__global__ __launch_bounds__(256)
void k1_scatter_gemm(const float* __restrict__ features,
                     const float* __restrict__ weight,
                     const int* __restrict__ pairs_in,
                     const int* __restrict__ pairs_out,
                     float* __restrict__ out,
                     int P, int rows_per_block)
{
    __shared__ bf16_t Wt[C_DIM * LDS_STRIDE];
    const int k   = blockIdx.y;
    const int tid = threadIdx.x;
    const float* Wk = weight + (size_t)k * C_DIM * C_DIM;
    for (int i = tid; i < C_DIM * C_DIM; i += 256) {
        int c = i >> 6, d = i & 63;
        Wt[d * LDS_STRIDE + c] = (bf16_t)Wk[i];
    }
    __syncthreads();
    const int wave = tid >> 6, lane = tid & 63, quad = lane >> 4, col = lane & 15;
    bf16x8 bfrag[2][4];
    #pragma unroll
    for (int ks = 0; ks < 2; ++ks)
        #pragma unroll
        for (int nt = 0; nt < 4; ++nt)
            bfrag[ks][nt] =
                *(const bf16x8*)&Wt[(col + 16 * nt) * LDS_STRIDE + quad * 8 + 32 * ks];
    const int* __restrict__ pin  = pairs_in  + (size_t)k * P;
    const int* __restrict__ pout = pairs_out + (size_t)k * P;
    const int p0   = blockIdx.x * rows_per_block;
    const int pend = min(p0 + rows_per_block, P);
    for (int base = p0 + wave * 16; base < pend; base += 64) {
        int prow    = base + col;
        int clamped = (prow < pend) ? prow : (pend - 1);
        int in_idx  = pin[clamped];
        int out_idx = pout[clamped];
        const float* src = features + (size_t)in_idx * C_DIM + quad * 8;
        float4 f0 = *(const float4*)(src);
        float4 f1 = *(const float4*)(src + 4);
        float4 f2 = *(const float4*)(src + 32);
        float4 f3 = *(const float4*)(src + 36);
        bf16x8 a0, a1;
        a0[0] = (bf16_t)f0.x; a0[1] = (bf16_t)f0.y; a0[2] = (bf16_t)f0.z; a0[3] = (bf16_t)f0.w;
        a0[4] = (bf16_t)f1.x; a0[5] = (bf16_t)f1.y; a0[6] = (bf16_t)f1.z; a0[7] = (bf16_t)f1.w;
        a1[0] = (bf16_t)f2.x; a1[1] = (bf16_t)f2.y; a1[2] = (bf16_t)f2.z; a1[3] = (bf16_t)f2.w;
        a1[4] = (bf16_t)f3.x; a1[5] = (bf16_t)f3.y; a1[6] = (bf16_t)f3.z; a1[7] = (bf16_t)f3.w;
        floatx4 acc0 = {0.f,0.f,0.f,0.f}, acc1 = {0.f,0.f,0.f,0.f};
        floatx4 acc2 = {0.f,0.f,0.f,0.f}, acc3 = {0.f,0.f,0.f,0.f};
        acc0 = __builtin_amdgcn_mfma_f32_16x16x32_bf16(a0, bfrag[0][0], acc0, 0, 0, 0);
        acc0 = __builtin_amdgcn_mfma_f32_16x16x32_bf16(a1, bfrag[1][0], acc0, 0, 0, 0);
        acc1 = __builtin_amdgcn_mfma_f32_16x16x32_bf16(a0, bfrag[0][1], acc1, 0, 0, 0);
        acc1 = __builtin_amdgcn_mfma_f32_16x16x32_bf16(a1, bfrag[1][1], acc1, 0, 0, 0);
        acc2 = __builtin_amdgcn_mfma_f32_16x16x32_bf16(a0, bfrag[0][2], acc2, 0, 0, 0);
        acc2 = __builtin_amdgcn_mfma_f32_16x16x32_bf16(a1, bfrag[1][2], acc2, 0, 0, 0);
        acc3 = __builtin_amdgcn_mfma_f32_16x16x32_bf16(a0, bfrag[0][3], acc3, 0, 0, 0);
        acc3 = __builtin_amdgcn_mfma_f32_16x16x32_bf16(a1, bfrag[1][3], acc3, 0, 0, 0);
        #pragma unroll
        for (int r = 0; r < 4; ++r) {
            int m = quad * 4 + r;
            int g = __shfl(out_idx, m);
            if (base + m < pend) {
                float* dst = out + (size_t)g * C_DIM + col;
                unsafeAtomicAdd(dst +  0, acc0[r]);
                unsafeAtomicAdd(dst + 16, acc1[r]);
                unsafeAtomicAdd(dst + 32, acc2[r]);
                unsafeAtomicAdd(dst + 48, acc3[r]);
            }
        }
    }
}

__global__ __launch_bounds__(256)
void k2_stats(const float* __restrict__ acc, float* __restrict__ sums, int n_rows)
{
    int tid = threadIdx.x;
    int ch  = tid & 63;
    int sub = tid >> 6;
    float s = 0.f, s2 = 0.f;
    for (int r = blockIdx.x * 4 + sub; r < n_rows; r += gridDim.x * 4) {
        float v = acc[(size_t)r * C_DIM + ch];
        s  += v;
        s2 += v * v;
    }
    __shared__ float red[256];
    red[tid] = s;
    __syncthreads();
    if (tid < 64) {
        float t = red[tid] + red[tid + 64] + red[tid + 128] + red[tid + 192];
        atomicAdd(&sums[ch], t);
    }
    __syncthreads();
    red[tid] = s2;
    __syncthreads();
    if (tid < 64) {
        float t = red[tid] + red[tid + 64] + red[tid + 128] + red[tid + 192];
        atomicAdd(&sums[64 + ch], t);
    }
}

// ============================================================================
extern "C" void kernel_launch(void* const* d_in, const int* in_sizes, int n_in,
                              void* d_out, int out_size, void* d_ws, size_t ws_size,
                              hipStream_t stream)
{
    const float* features  = (const float*)d_in[0];
    const float* weight    = (const float*)d_in[1];
    // d_in[2] = bias (cancels in training-mode BN)
    const float* gamma     = (const float*)d_in[3];
    const float* beta      = (const float*)d_in[4];
    const int*   pairs_in  = (const int*)d_in[5];
    const int*   pairs_out = (const int*)d_in[6];

    const int n_out = out_size / C_DIM;
    const int K3    = in_sizes[1] / (C_DIM * C_DIM);
    const int P     = in_sizes[5] / K3;
    const int M     = in_sizes[5];          // K3 * P pairs total

    float* out = (float*)d_out;

    // workspace layout
    const int nb = (n_out + 1023) / 1024;   // scan blocks
    float* sums   = (float*)d_ws;                        // 128 floats (512 B)
    int*   offsets = (int*)((char*)d_ws + 512);          // n_out + 1
    int*   cursor  = offsets + (n_out + 1);              // n_out
    int*   partials = cursor + n_out;                    // nb
    size_t head_bytes = 512 + (size_t)(2 * n_out + 1 + nb) * 4;
    size_t temp_off   = (head_bytes + 255) & ~(size_t)255;
    size_t need       = temp_off + (size_t)M * 128;

    if (ws_size >= need && nb <= 1024) {
        char* temp = (char*)d_ws + temp_off;

        // zero sums + counts (cursor); offsets/partials are fully overwritten
        hipMemsetAsync(d_ws, 0, 512 + (size_t)(2 * n_out + 1) * 4, stream);

        k_hist<<<(M + 255) / 256, 256, 0, stream>>>(pairs_out, cursor, M);
        k_scan_a<<<nb, 256, 0, stream>>>(cursor, partials, n_out);
        k_scan_b<<<1, 1024, 0, stream>>>(partials, nb);
        k_scan_c<<<nb, 256, 0, stream>>>(cursor, offsets, partials, n_out, M);

        const int rows_per_block = 512;
        dim3 g1((P + rows_per_block - 1) / rows_per_block, K3);
        k_gemm_store<<<g1, 256, 0, stream>>>(features, weight, pairs_in,
                                             pairs_out, cursor, temp,
                                             P, rows_per_block);

        k_gather_sum<<<dim3(2048), 256, 0, stream>>>(temp, offsets, out, sums, n_out);

        k3_bn_relu<<<dim3(512), 256, 0, stream>>>(out, sums, gamma, beta, n_out);
    } else {
        // fallback: R1 atomic-scatter path
        hipMemsetAsync(d_out, 0, (size_t)out_size * sizeof(float), stream);
        hipMemsetAsync(d_ws, 0, 128 * sizeof(float), stream);

        const int rows_per_block = 512;
        dim3 g1((P + rows_per_block - 1) / rows_per_block, K3);
        k1_scatter_gemm<<<g1, 256, 0, stream>>>(features, weight, pairs_in,
                                                pairs_out, out, P, rows_per_block);
        k2_stats<<<dim3(512), 256, 0, stream>>>(out, sums, n_out);
        k3_bn_relu<<<dim3(512), 256, 0, stream>>>(out, sums, gamma, beta, n_out);
    }
}

// Round 3
// 591.084 us; speedup vs baseline: 1.0047x; 1.0047x over previous
//
#include <hip/hip_runtime.h>

// SparseConvTransposeBlock, round 3: row-contiguous 256B atomic scatter.
//
// R1/R2 evidence: scatter issues 4x 64B RMW segments per output row
// (8.6M segments, ~19G seg/s -> 1.8 TB/s -> 447us). ws_size < 278MB so the
// CSR temp path can never run (R2 fell back). This round keeps the proven
// atomic path but repacks each 16x64 product tile through per-wave LDS so
// each output row is written by ONE wave-wide atomic instruction: 64 lanes
// x 4B = 256B contiguous RMW per row (2.16M segments instead of 8.6M).
// fp32 atomics -> absmax unchanged (0.03125).
//
// Bias cancels in training-mode BN: y = (acc - mean_acc)*rsqrt(var)*g + b.

#define C_DIM 64
#define LDS_STRIDE 72   // bf16 elems per Wt row: 64 + 8 pad
#define ROW_STRIDE 68   // fp32 elems per scratch row: 64 + 4 pad (2-way only)

typedef __bf16 bf16_t;
typedef bf16_t bf16x8 __attribute__((ext_vector_type(8)));
typedef float floatx4 __attribute__((ext_vector_type(4)));

__global__ __launch_bounds__(256)
void k1_row_atomic(const float* __restrict__ features,
                   const float* __restrict__ weight,
                   const int* __restrict__ pairs_in,
                   const int* __restrict__ pairs_out,
                   float* __restrict__ out,
                   int P, int rows_per_block)
{
    __shared__ bf16_t Wt[C_DIM * LDS_STRIDE];
    __shared__ float  scratch[4][16 * ROW_STRIDE];  // per-wave 16x64 tile

    const int k   = blockIdx.y;
    const int tid = threadIdx.x;

    // Stage W_k^T into LDS as bf16: Wt[d][c] = W[k][c][d].
    const float* Wk = weight + (size_t)k * C_DIM * C_DIM;
    for (int i = tid; i < C_DIM * C_DIM; i += 256) {
        int c = i >> 6, d = i & 63;
        Wt[d * LDS_STRIDE + c] = (bf16_t)Wk[i];
    }
    __syncthreads();

    const int wave = tid >> 6;
    const int lane = tid & 63;
    const int quad = lane >> 4;
    const int col  = lane & 15;
    float* ls = &scratch[wave][0];

    // B fragments: lane holds B[kk = quad*8+j+32*ks][n = col+16*nt] = Wt[n][kk].
    bf16x8 bfrag[2][4];
    #pragma unroll
    for (int ks = 0; ks < 2; ++ks)
        #pragma unroll
        for (int nt = 0; nt < 4; ++nt)
            bfrag[ks][nt] =
                *(const bf16x8*)&Wt[(col + 16 * nt) * LDS_STRIDE + quad * 8 + 32 * ks];

    const int* __restrict__ pin  = pairs_in  + (size_t)k * P;
    const int* __restrict__ pout = pairs_out + (size_t)k * P;

    const int p0   = blockIdx.x * rows_per_block;
    const int pend = min(p0 + rows_per_block, P);

    for (int base = p0 + wave * 16; base < pend; base += 64) {
        // Lane mirrors row (base + col); quads replicate the 16 rows.
        int prow    = base + col;
        int clamped = (prow < pend) ? prow : (pend - 1);
        int in_idx  = pin[clamped];
        int out_idx = pout[clamped];   // valid on lanes 0..15

        // Gather A fragments in MFMA A-layout:
        // A[m = col][kk = quad*8 + j + 32*ks] = features[in_idx][kk].
        const float* src = features + (size_t)in_idx * C_DIM + quad * 8;
        float4 f0 = *(const float4*)(src);
        float4 f1 = *(const float4*)(src + 4);
        float4 f2 = *(const float4*)(src + 32);
        float4 f3 = *(const float4*)(src + 36);

        bf16x8 a0, a1;
        a0[0] = (bf16_t)f0.x; a0[1] = (bf16_t)f0.y; a0[2] = (bf16_t)f0.z; a0[3] = (bf16_t)f0.w;
        a0[4] = (bf16_t)f1.x; a0[5] = (bf16_t)f1.y; a0[6] = (bf16_t)f1.z; a0[7] = (bf16_t)f1.w;
        a1[0] = (bf16_t)f2.x; a1[1] = (bf16_t)f2.y; a1[2] = (bf16_t)f2.z; a1[3] = (bf16_t)f2.w;
        a1[4] = (bf16_t)f3.x; a1[5] = (bf16_t)f3.y; a1[6] = (bf16_t)f3.z; a1[7] = (bf16_t)f3.w;

        floatx4 acc0 = {0.f, 0.f, 0.f, 0.f};
        floatx4 acc1 = {0.f, 0.f, 0.f, 0.f};
        floatx4 acc2 = {0.f, 0.f, 0.f, 0.f};
        floatx4 acc3 = {0.f, 0.f, 0.f, 0.f};

        acc0 = __builtin_amdgcn_mfma_f32_16x16x32_bf16(a0, bfrag[0][0], acc0, 0, 0, 0);
        acc0 = __builtin_amdgcn_mfma_f32_16x16x32_bf16(a1, bfrag[1][0], acc0, 0, 0, 0);
        acc1 = __builtin_amdgcn_mfma_f32_16x16x32_bf16(a0, bfrag[0][1], acc1, 0, 0, 0);
        acc1 = __builtin_amdgcn_mfma_f32_16x16x32_bf16(a1, bfrag[1][1], acc1, 0, 0, 0);
        acc2 = __builtin_amdgcn_mfma_f32_16x16x32_bf16(a0, bfrag[0][2], acc2, 0, 0, 0);
        acc2 = __builtin_amdgcn_mfma_f32_16x16x32_bf16(a1, bfrag[1][2], acc2, 0, 0, 0);
        acc3 = __builtin_amdgcn_mfma_f32_16x16x32_bf16(a0, bfrag[0][3], acc3, 0, 0, 0);
        acc3 = __builtin_amdgcn_mfma_f32_16x16x32_bf16(a1, bfrag[1][3], acc3, 0, 0, 0);

        // Repack C tile into per-wave LDS: ls[m][ch], m = quad*4+r, ch = col+16j.
        // Bank math (stride 68): per store instr quads alias 2-way only -> free.
        #pragma unroll
        for (int r = 0; r < 4; ++r) {
            int m = quad * 4 + r;
            ls[m * ROW_STRIDE + col +  0] = acc0[r];
            ls[m * ROW_STRIDE + col + 16] = acc1[r];
            ls[m * ROW_STRIDE + col + 32] = acc2[r];
            ls[m * ROW_STRIDE + col + 48] = acc3[r];
        }
        // Scratch is wave-private: wave-level LDS drain only (NOT vmcnt --
        // outstanding no-return atomics must stay in flight).
        asm volatile("s_waitcnt lgkmcnt(0)" ::: "memory");

        // One wave-wide atomic per output row: 64 lanes x 4B = 256B contiguous.
        #pragma unroll
        for (int m = 0; m < 16; ++m) {
            if (base + m < pend) {
                float v = ls[m * ROW_STRIDE + lane];
                int   g = __shfl(out_idx, m);   // lane m (<16) holds row base+m's index
                unsafeAtomicAdd(out + (size_t)g * C_DIM + lane, v);
            }
        }
        // Next iteration overwrites scratch only after these ds_reads retire
        // (compiler orders ds ops within the wave via lgkmcnt).
    }
}

// Per-channel sum and sum-of-squares over all rows of acc (pre-BN output).
__global__ __launch_bounds__(256)
void k2_stats(const float* __restrict__ acc, float* __restrict__ sums, int n_rows)
{
    const int tid    = threadIdx.x;
    const int lanec  = tid & 15;    // channel group: 4 consecutive channels
    const int rowoff = tid >> 4;    // 16 rows per block pass

    float s[4]  = {0.f, 0.f, 0.f, 0.f};
    float s2[4] = {0.f, 0.f, 0.f, 0.f};

    for (int r = blockIdx.x * 16 + rowoff; r < n_rows; r += gridDim.x * 16) {
        float4 v = *(const float4*)&acc[(size_t)r * C_DIM + lanec * 4];
        s[0] += v.x; s2[0] += v.x * v.x;
        s[1] += v.y; s2[1] += v.y * v.y;
        s[2] += v.z; s2[2] += v.z * v.z;
        s[3] += v.w; s2[3] += v.w * v.w;
    }

    __shared__ float ls[128];
    if (tid < 128) ls[tid] = 0.f;
    __syncthreads();
    #pragma unroll
    for (int j = 0; j < 4; ++j) {
        atomicAdd(&ls[lanec * 4 + j], s[j]);
        atomicAdd(&ls[64 + lanec * 4 + j], s2[j]);
    }
    __syncthreads();
    if (tid < 128) atomicAdd(&sums[tid], ls[tid]);
}

// In-place BN (training stats) + ReLU. Bias cancels (see header).
__global__ __launch_bounds__(256)
void k3_bn_relu(float* __restrict__ out, const float* __restrict__ sums,
                const float* __restrict__ gamma, const float* __restrict__ beta,
                int n_rows)
{
    int tid = blockIdx.x * 256 + threadIdx.x;
    int ch0 = (tid * 4) & 63;  // stride is a multiple of 64 elems -> fixed channels
    float inv_n = 1.0f / (float)n_rows;

    float sc[4], sh[4];
    #pragma unroll
    for (int j = 0; j < 4; ++j) {
        int ch    = ch0 + j;
        float m   = sums[ch] * inv_n;
        float var = sums[64 + ch] * inv_n - m * m;
        float inv = rsqrtf(var + 1e-5f);
        float g   = gamma[ch] * inv;
        sc[j] = g;
        sh[j] = beta[ch] - m * g;
    }

    size_t total = (size_t)n_rows * C_DIM / 4;
    for (size_t i = tid; i < total; i += (size_t)gridDim.x * 256) {
        float4 v = ((const float4*)out)[i];
        v.x = fmaxf(v.x * sc[0] + sh[0], 0.f);
        v.y = fmaxf(v.y * sc[1] + sh[1], 0.f);
        v.z = fmaxf(v.z * sc[2] + sh[2], 0.f);
        v.w = fmaxf(v.w * sc[3] + sh[3], 0.f);
        ((float4*)out)[i] = v;
    }
}

extern "C" void kernel_launch(void* const* d_in, const int* in_sizes, int n_in,
                              void* d_out, int out_size, void* d_ws, size_t ws_size,
                              hipStream_t stream)
{
    const float* features  = (const float*)d_in[0];
    const float* weight    = (const float*)d_in[1];
    // d_in[2] = bias (cancels in training-mode BN)
    const float* gamma     = (const float*)d_in[3];
    const float* beta      = (const float*)d_in[4];
    const int*   pairs_in  = (const int*)d_in[5];
    const int*   pairs_out = (const int*)d_in[6];

    const int n_out = out_size / C_DIM;
    const int K3    = in_sizes[1] / (C_DIM * C_DIM);
    const int P     = in_sizes[5] / K3;

    float* out  = (float*)d_out;
    float* sums = (float*)d_ws;  // [64] sum, [64] sumsq

    hipMemsetAsync(d_out, 0, (size_t)out_size * sizeof(float), stream);
    hipMemsetAsync(d_ws, 0, 128 * sizeof(float), stream);

    const int rows_per_block = 512;
    dim3 g1((P + rows_per_block - 1) / rows_per_block, K3);
    k1_row_atomic<<<g1, 256, 0, stream>>>(features, weight, pairs_in, pairs_out,
                                          out, P, rows_per_block);

    k2_stats<<<dim3(1024), 256, 0, stream>>>(out, sums, n_out);

    k3_bn_relu<<<dim3(1024), 256, 0, stream>>>(out, sums, gamma, beta, n_out);
}